// Round 5
// baseline (94.268 us; speedup 1.0000x reference)
//
#include <hip/hip_runtime.h>
#include <cstdint>
#include <cstddef>

#define N_ROWS 8192
#define DDIM   128
// logits (natural) = dot * 50. We work in log2 units: L2 = dot * K2.
// Fixed softmax shift = K2 (max possible logit2 since |dot| <= 1): no
// online max needed; terms exp2(dot*K2 - K2) are always in [2^-145, 1].
#define K2  72.13475204444817f   // 50 / ln(2)
#define LN2 0.6931471805599453f
#define NPART 16                 // 8 col-splits x 2 col-waves

typedef _Float16 f16x8 __attribute__((ext_vector_type(8)));
typedef _Float16 f16x4 __attribute__((ext_vector_type(4)));
typedef float    f32x4 __attribute__((ext_vector_type(4)));

typedef const __attribute__((address_space(1))) void GVp;
typedef __attribute__((address_space(3))) void LVp;

__device__ __forceinline__ void gload_lds16(const void* g, void* l) {
  __builtin_amdgcn_global_load_lds((GVp*)g, (LVp*)l, 16, 0, 0);
}

// fast transcendentals: v_exp_f32 computes 2^x, v_log_f32 computes log2(x)
__device__ __forceinline__ float ex2(float x) { return __builtin_amdgcn_exp2f(x); }
__device__ __forceinline__ float lg2(float x) { return __builtin_amdgcn_logf(x); }

// ---------------------------------------------------------------------------
// prep: fp32 [8192][128] x2 -> L2-normalized fp16 row-major x2 + exact fp32
// diagonal logit (log2 units). 32 lanes per row, 8 rows per 256-thr block.
// ---------------------------------------------------------------------------
__global__ __launch_bounds__(256) void prep(const float* __restrict__ ts,
                                            const float* __restrict__ sq,
                                            _Float16* __restrict__ tsH,
                                            _Float16* __restrict__ sqH,
                                            float* __restrict__ diag2) {
  const int row = blockIdx.x * 8 + (threadIdx.x >> 5);
  const int g   = threadIdx.x & 31;
  const size_t base = (size_t)row * DDIM;

  const float4 a = reinterpret_cast<const float4*>(ts + base)[g];
  const float4 b = reinterpret_cast<const float4*>(sq + base)[g];

  float ssa = a.x * a.x + a.y * a.y + a.z * a.z + a.w * a.w;
  float ssb = b.x * b.x + b.y * b.y + b.z * b.z + b.w * b.w;
  float cr  = a.x * b.x + a.y * b.y + a.z * b.z + a.w * b.w;
  #pragma unroll
  for (int mask = 1; mask <= 16; mask <<= 1) {   // reduce within 32-lane group
    ssa += __shfl_xor(ssa, mask);
    ssb += __shfl_xor(ssb, mask);
    cr  += __shfl_xor(cr,  mask);
  }
  const float ra = 1.0f / fmaxf(sqrtf(ssa), 1e-12f);
  const float rb = 1.0f / fmaxf(sqrtf(ssb), 1e-12f);

  f16x4 ha, hb;
  ha[0] = (_Float16)(a.x * ra); ha[1] = (_Float16)(a.y * ra);
  ha[2] = (_Float16)(a.z * ra); ha[3] = (_Float16)(a.w * ra);
  hb[0] = (_Float16)(b.x * rb); hb[1] = (_Float16)(b.y * rb);
  hb[2] = (_Float16)(b.z * rb); hb[3] = (_Float16)(b.w * rb);
  *reinterpret_cast<f16x4*>(tsH + base + g * 4) = ha;
  *reinterpret_cast<f16x4*>(sqH + base + g * 4) = hb;

  if (g == 0) diag2[row] = cr * ra * rb * K2;   // exact fp32 diagonal, log2 units
}

// ---------------------------------------------------------------------------
// lse16: fixed-shift streaming sum of exp2(logit2 - K2) where
// logit2 = (tsH . sqH^T) * K2, via v_mfma_f32_16x16x32_f16.
// Block tile 128x128, 4 waves in 2x2, wave tile 64x64 (4x4 fragments).
// A-fragments VGPR-resident; B double-buffered in LDS in fragment-linear
// layout (conflict-free lane-linear ds_read_b128).
// Writes per-(row, colsplit*2+wc) partial sum s.
// ---------------------------------------------------------------------------
__global__ __launch_bounds__(256, 2) void lse16(const _Float16* __restrict__ tsH,
                                                const _Float16* __restrict__ sqH,
                                                float* __restrict__ s_part) {
  __shared__ f16x8 Bl[2][4][8][64];   // [buf][kstep][colgroup16][lane] = 64 KB

  const int tid = threadIdx.x;
  const int l   = tid & 63;
  const int wid = tid >> 6;
  const int wr  = wid >> 1;           // wave row (0..1)
  const int wc  = wid & 1;            // wave col (0..1)
  const int lm  = l & 15;             // fragment 16-index
  const int lk  = l >> 4;             // fragment k-group (0..3)

  const int rowbase  = blockIdx.x * 128 + wr * 64;   // wave's 64 rows
  const int colbase0 = blockIdx.y * 1024;            // this split's 1024 cols
  const int sp       = blockIdx.y;

  // ---- A fragments: resident for the whole kernel (4 ri x 4 ksteps) ----
  // lane l holds A[row = rowbase+ri*16+(l&15)][k = ks*32+(l>>4)*8 .. +7]
  f16x8 af[4][4];
  #pragma unroll
  for (int ri = 0; ri < 4; ++ri) {
    const size_t arow = (size_t)(rowbase + ri * 16 + lm) * DDIM;
    #pragma unroll
    for (int ks = 0; ks < 4; ++ks)
      af[ri][ks] = *reinterpret_cast<const f16x8*>(tsH + arow + ks * 32 + lk * 8);
  }

  // per-lane staging source: wave `wid` stages kstep==wid for all 8 colgroups.
  // Bl[b][wid][cg][l] <- sq[colbase + cg*16 + (l&15)][wid*32 + (l>>4)*8 ..+7]
  const _Float16* sgp = sqH + (size_t)(colbase0 + lm) * DDIM + wid * 32 + lk * 8;

  f32x4 acc[4][4];
  float sreg[4][4];
  #pragma unroll
  for (int i = 0; i < 4; ++i)
    #pragma unroll
    for (int j = 0; j < 4; ++j) sreg[i][j] = 0.f;

  auto stage = [&](int b, int ct) {
    #pragma unroll
    for (int cg = 0; cg < 8; ++cg)
      gload_lds16(sgp + (size_t)(ct * 128 + cg * 16) * DDIM, &Bl[b][wid][cg][0]);
  };

  stage(0, 0);
  int buf = 0;
  #pragma unroll 1
  for (int ct = 0; ct < 8; ++ct) {
    __syncthreads();                    // drains vmcnt (stage) + lgkmcnt (reads)
    if (ct < 7) stage(buf ^ 1, ct + 1);

    #pragma unroll
    for (int i = 0; i < 4; ++i)
      #pragma unroll
      for (int j = 0; j < 4; ++j) acc[i][j] = f32x4{0.f, 0.f, 0.f, 0.f};

    #pragma unroll
    for (int ks = 0; ks < 4; ++ks) {
      f16x8 bf[4];
      #pragma unroll
      for (int cj = 0; cj < 4; ++cj) bf[cj] = Bl[buf][ks][wc * 4 + cj][l];
      #pragma unroll
      for (int ri = 0; ri < 4; ++ri)
        #pragma unroll
        for (int cj = 0; cj < 4; ++cj)
          acc[ri][cj] = __builtin_amdgcn_mfma_f32_16x16x32_f16(af[ri][ks], bf[cj],
                                                               acc[ri][cj], 0, 0, 0);
    }

    // fixed-shift exp2 accumulate.
    // lane owns rows rowbase+ri*16+lk*4+r, cols ct*128+(wc*4+cj)*16+lm.
    #pragma unroll
    for (int ri = 0; ri < 4; ++ri)
      #pragma unroll
      for (int r = 0; r < 4; ++r) {
        const float e0 = ex2(fmaf(acc[ri][0][r], K2, -K2));
        const float e1 = ex2(fmaf(acc[ri][1][r], K2, -K2));
        const float e2 = ex2(fmaf(acc[ri][2][r], K2, -K2));
        const float e3 = ex2(fmaf(acc[ri][3][r], K2, -K2));
        sreg[ri][r] += (e0 + e1) + (e2 + e3);
      }
    buf ^= 1;
  }

  // sum across the 16 lanes (same lk group) holding each row's columns
  #pragma unroll
  for (int ri = 0; ri < 4; ++ri)
    #pragma unroll
    for (int r = 0; r < 4; ++r) {
      float s = sreg[ri][r];
      s += __shfl_xor(s, 1);
      s += __shfl_xor(s, 2);
      s += __shfl_xor(s, 4);
      s += __shfl_xor(s, 8);
      if (lm == 0) {
        // each (sp, wc) pair covers a distinct 512-col strip -> distinct slot
        const int row = rowbase + ri * 16 + lk * 4 + r;
        s_part[(sp * 2 + wc) * N_ROWS + row] = s;
      }
    }
}

// ---------------------------------------------------------------------------
// row_combine: sum 16 strip partials per row, lse2 = K2 + log2(S), apply
// mask, deterministic block reduction (no atomics -> graph-replay stable).
// ---------------------------------------------------------------------------
__global__ __launch_bounds__(256) void row_combine(const float* __restrict__ s_part,
                                                   const float* __restrict__ diag2,
                                                   const int* __restrict__ patch_mask,
                                                   float* __restrict__ bp) {
  const int row = blockIdx.x * 256 + threadIdx.x;
  float S = 0.f;
  #pragma unroll
  for (int j = 0; j < NPART; ++j) S += s_part[j * N_ROWS + row];
  const float lse2 = K2 + lg2(fmaxf(S, 1e-37f));       // log2-domain LSE
  const float pm   = (float)patch_mask[row];
  float c = pm * LN2 * (diag2[row] - lse2);            // natural-log contribution
  float p = pm;
  #pragma unroll
  for (int mask = 1; mask < 64; mask <<= 1) {
    c += __shfl_xor(c, mask);
    p += __shfl_xor(p, mask);
  }
  __shared__ float rc[4], rp[4];
  const int w = threadIdx.x >> 6;
  if ((threadIdx.x & 63) == 0) { rc[w] = c; rp[w] = p; }
  __syncthreads();
  if (threadIdx.x == 0) {
    bp[blockIdx.x * 2]     = rc[0] + rc[1] + rc[2] + rc[3];
    bp[blockIdx.x * 2 + 1] = rp[0] + rp[1] + rp[2] + rp[3];
  }
}

__global__ __launch_bounds__(64) void finalize(const float* __restrict__ bp,
                                               float* __restrict__ out) {
  const int t = threadIdx.x;
  float c = (t < 32) ? bp[t * 2]     : 0.f;
  float p = (t < 32) ? bp[t * 2 + 1] : 0.f;
  #pragma unroll
  for (int mask = 1; mask < 64; mask <<= 1) {
    c += __shfl_xor(c, mask);
    p += __shfl_xor(p, mask);
  }
  if (t == 0) out[0] = -c / (p + 1e-6f);
}

// ---------------------------------------------------------------------------
extern "C" void kernel_launch(void* const* d_in, const int* in_sizes, int n_in,
                              void* d_out, int out_size, void* d_ws, size_t ws_size,
                              hipStream_t stream) {
  const float* ts    = (const float*)d_in[0];
  const float* sq    = (const float*)d_in[1];
  const int*   pmask = (const int*)d_in[3];

  char* w = (char*)d_ws;
  _Float16* tsH    = (_Float16*)w;                          // 2 MB
  _Float16* sqH    = (_Float16*)(w + (2u << 20));           // 2 MB
  float*    diag2  = (float*)(w + (4u << 20));              // 32 KB
  float*    s_part = diag2 + N_ROWS;                        // 16*8192 f
  float*    bp     = s_part + NPART * N_ROWS;               // 64 f

  prep<<<N_ROWS / 8, 256, 0, stream>>>(ts, sq, tsH, sqH, diag2);
  lse16<<<dim3(64, 8), 256, 0, stream>>>(tsH, sqH, s_part);
  row_combine<<<N_ROWS / 256, 256, 0, stream>>>(s_part, diag2, pmask, bp);
  finalize<<<1, 64, 0, stream>>>(bp, (float*)d_out);
}